// Round 11
// baseline (469.734 us; speedup 1.0000x reference)
//
#include <hip/hip_runtime.h>
#include <hip/hip_bf16.h>

#define N_NODES 100000
#define N_EDGES 1600000
#define NODE_DIM 128
#define MEM 64
#define NEG_SLOPE 0.2f
#define NB ((N_NODES + 255) / 256)  // 391 scan blocks

typedef __attribute__((ext_vector_type(8))) short short8;
typedef __attribute__((ext_vector_type(4))) float f32x4;

__device__ __forceinline__ float lrelu(float v) { return v >= 0.f ? v : NEG_SLOPE * v; }

// f32 -> bf16 (RNE) bit pattern
__device__ __forceinline__ unsigned short bfr(float f) {
    unsigned u = __float_as_uint(f);
    u = (u + 0x7FFFu + ((u >> 16) & 1u)) >> 16;
    return (unsigned short)u;
}
__device__ __forceinline__ float bf2f(unsigned short s) {
    return __uint_as_float(((unsigned)s) << 16);
}

// Kernel A (MFMA): per 16-node tile:
//   proj = state@w_in.T + b_in (4 MFMAs, K=128); me = proj+goal+mem -> global bf16 + LDS bf16
//   xt   = me@w_gat.T          (2 MFMAs, K=64)  -> global bf16
//   a_s/a_d via shfl col-reduce + LDS cross-wave combine
__global__ __launch_bounds__(256) void kA(
    const float* __restrict__ state, const float* __restrict__ goal,
    const float* __restrict__ mem, const float* __restrict__ w_in,
    const float* __restrict__ b_in, const float* __restrict__ w_gat,
    const float* __restrict__ att_src, const float* __restrict__ att_dst,
    unsigned short* __restrict__ me_out, unsigned short* __restrict__ xt_out,
    float* __restrict__ as_out, float* __restrict__ ad_out)
{
    __shared__ unsigned short s_me[16][72];  // bf16 me tile; 144B row stride (16B aligned)
    __shared__ float s_red[4][16][2];        // per-wave (a_s,a_d) partials
    const int wv = threadIdx.x >> 6;
    const int lane = threadIdx.x & 63;
    const int lr = lane & 15;                // A-row / B-col / D-col
    const int lk = lane >> 4;                // k-block / D row-block
    const int col = wv * 16 + lr;

    short8 Bp[4], Bx[2];
    #pragma unroll
    for (int s = 0; s < 4; ++s) {
        const float* p = w_in + (long)col * NODE_DIM + s * 32 + lk * 8;
        short8 b;
        #pragma unroll
        for (int t = 0; t < 8; ++t) b[t] = (short)bfr(p[t]);
        Bp[s] = b;
    }
    #pragma unroll
    for (int s = 0; s < 2; ++s) {
        const float* p = w_gat + (long)col * MEM + s * 32 + lk * 8;
        short8 b;
        #pragma unroll
        for (int t = 0; t < 8; ++t) b[t] = (short)bfr(p[t]);
        Bx[s] = b;
    }
    const float bcol = b_in[col];
    const float av_s = att_src[col], av_d = att_dst[col];

    for (int mt = blockIdx.x; mt < N_NODES / 16; mt += gridDim.x) {
        const int n0 = mt * 16;
        short8 Ap[4];
        #pragma unroll
        for (int s = 0; s < 4; ++s) {
            const float* p = state + (long)(n0 + lr) * NODE_DIM + s * 32 + lk * 8;
            short8 a;
            #pragma unroll
            for (int t = 0; t < 8; ++t) a[t] = (short)bfr(p[t]);
            Ap[s] = a;
        }
        f32x4 accp;
        accp[0] = bcol; accp[1] = bcol; accp[2] = bcol; accp[3] = bcol;
        #pragma unroll
        for (int s = 0; s < 4; ++s)
            accp = __builtin_amdgcn_mfma_f32_16x16x32_bf16(Ap[s], Bp[s], accp, 0, 0, 0);
        unsigned short mev[4];
        #pragma unroll
        for (int r = 0; r < 4; ++r) {
            const long off = (long)(n0 + lk * 4 + r) * MEM + col;
            const float v = accp[r] + goal[off] + mem[off];
            mev[r] = bfr(v);
            me_out[off] = mev[r];
        }
        __syncthreads();   // previous tile's s_me / s_red reads complete
        #pragma unroll
        for (int r = 0; r < 4; ++r) s_me[lk * 4 + r][col] = mev[r];
        __syncthreads();   // s_me ready
        short8 Ax2[2];
        #pragma unroll
        for (int s = 0; s < 2; ++s)
            Ax2[s] = *(const short8*)&s_me[lr][s * 32 + lk * 8];
        f32x4 accx;
        accx[0] = 0.f; accx[1] = 0.f; accx[2] = 0.f; accx[3] = 0.f;
        #pragma unroll
        for (int s = 0; s < 2; ++s)
            accx = __builtin_amdgcn_mfma_f32_16x16x32_bf16(Ax2[s], Bx[s], accx, 0, 0, 0);
        float ps[4], pd[4];
        #pragma unroll
        for (int r = 0; r < 4; ++r) {
            const float xv = accx[r];
            xt_out[(long)(n0 + lk * 4 + r) * MEM + col] = bfr(xv);
            ps[r] = xv * av_s;
            pd[r] = xv * av_d;
        }
        #pragma unroll
        for (int r = 0; r < 4; ++r) {
            #pragma unroll
            for (int o = 1; o < 16; o <<= 1) {
                ps[r] += __shfl_xor(ps[r], o);
                pd[r] += __shfl_xor(pd[r], o);
            }
        }
        if (lr == 0) {
            #pragma unroll
            for (int r = 0; r < 4; ++r) {
                s_red[wv][lk * 4 + r][0] = ps[r];
                s_red[wv][lk * 4 + r][1] = pd[r];
            }
        }
        __syncthreads();   // s_red ready
        if (threadIdx.x < 32) {
            const int node = threadIdx.x >> 1, sel = threadIdx.x & 1;
            const float v = s_red[0][node][sel] + s_red[1][node][sel] +
                            s_red[2][node][sel] + s_red[3][node][sel];
            if (sel == 0) as_out[n0 + node] = v;
            else          ad_out[n0 + node] = v;
        }
    }
}

// Kernel H: in-degree histogram, int4 edge reads (4 edges/thread)
__global__ __launch_bounds__(256) void kH(const int4* __restrict__ dst4, int* __restrict__ deg) {
    const int i = blockIdx.x * 256 + threadIdx.x;
    if (i < N_EDGES / 4) {
        const int4 d = dst4[i];
        atomicAdd(deg + d.x, 1);
        atomicAdd(deg + d.y, 1);
        atomicAdd(deg + d.z, 1);
        atomicAdd(deg + d.w, 1);
    }
}

// Scan kernel 1: per-256-block sums of deg
__global__ __launch_bounds__(256) void kS1(const int* __restrict__ deg, int* __restrict__ bsums) {
    const int i = blockIdx.x * 256 + threadIdx.x;
    int s = (i < N_NODES) ? deg[i] : 0;
    #pragma unroll
    for (int o = 32; o; o >>= 1) s += __shfl_xor(s, o);
    __shared__ int ws_[4];
    if ((threadIdx.x & 63) == 0) ws_[threadIdx.x >> 6] = s;
    __syncthreads();
    if (threadIdx.x == 0) bsums[blockIdx.x] = ws_[0] + ws_[1] + ws_[2] + ws_[3];
}

// Scan kernel 2: exclusive scan of NB block sums (single block)
__global__ __launch_bounds__(512) void kS2(int* __restrict__ bsums) {
    const int t = threadIdx.x;
    int v = (t < NB) ? bsums[t] : 0;
    int x = v;
    #pragma unroll
    for (int o = 1; o < 64; o <<= 1) {
        int y = __shfl_up(x, o);
        if ((t & 63) >= o) x += y;
    }
    __shared__ int wt[8];
    if ((t & 63) == 63) wt[t >> 6] = x;
    __syncthreads();
    int woff = 0;
    for (int w = 0; w < (t >> 6); ++w) woff += wt[w];
    if (t < NB) bsums[t] = woff + x - v;  // exclusive
}

// Scan kernel 3: per-block exclusive scan + block offset -> row_ptr, cursor
__global__ __launch_bounds__(256) void kS3(const int* __restrict__ deg, const int* __restrict__ bsums,
                                           int* __restrict__ row_ptr, int* __restrict__ cursor) {
    const int i = blockIdx.x * 256 + threadIdx.x;
    const int t = threadIdx.x;
    int v = (i < N_NODES) ? deg[i] : 0;
    int x = v;
    #pragma unroll
    for (int o = 1; o < 64; o <<= 1) {
        int y = __shfl_up(x, o);
        if ((t & 63) >= o) x += y;
    }
    __shared__ int wt[4];
    if ((t & 63) == 63) wt[t >> 6] = x;
    __syncthreads();
    int woff = bsums[blockIdx.x];
    for (int w = 0; w < (t >> 6); ++w) woff += wt[w];
    const int excl = woff + x - v;
    if (i < N_NODES) {
        row_ptr[i] = excl;
        cursor[i] = excl;
        if (i == N_NODES - 1) row_ptr[N_NODES] = excl + v;
    }
}

// Kernel P: place src into CSR slots (4B payload; logit recomputed in kG)
__global__ __launch_bounds__(256) void kP(
    const int* __restrict__ src, const int* __restrict__ dst,
    int* __restrict__ cursor, int* __restrict__ csrS)
{
    const int e = blockIdx.x * 256 + threadIdx.x;
    if (e >= N_EDGES) return;
    const int slot = atomicAdd(cursor + dst[e], 1);
    csrS[slot] = src[e];
}

// Kernel G v4: wave per node, SINGLE PASS (no max phase; normalize by exp(e - e_self);
// softmax shift-invariant, logits O(±10) so no overflow). Half-wave parity edge split;
// per-lane 4B xt gathers; csr/as loads are half-wave broadcasts.
// me (bf16) RMW in place: x = me + ctx + b_gat. Self-loop weight = 1 exactly.
__global__ __launch_bounds__(256) void kG(
    const int* __restrict__ row_ptr, const int* __restrict__ csrS,
    const float* __restrict__ as_, const float* __restrict__ ad_,
    const unsigned short* __restrict__ xt, const float* __restrict__ b_gat,
    unsigned short* __restrict__ me /* bf16, in: mem_enh, out: x */)
{
    const int wave = threadIdx.x >> 6, lane = threadIdx.x & 63;
    const int eo = lane >> 5, c2 = lane & 31;
    const float bg0 = b_gat[2 * c2], bg1 = b_gat[2 * c2 + 1];
    for (int node = blockIdx.x * 4 + wave; node < N_NODES; node += gridDim.x * 4) {
        const int beg = row_ptr[node], end = row_ptr[node + 1];
        const float adn = ad_[node];
        const float e_self = lrelu(as_[node] + adn);
        float acc0 = 0.f, acc1 = 0.f, den = 0.f;
        int j = beg + eo;
        for (; j + 2 < end; j += 4) {
            const int sa = csrS[j], sb = csrS[j + 2];
            const unsigned ua = *(const unsigned*)&xt[((unsigned)sa << 6) + 2 * c2];
            const unsigned ub = *(const unsigned*)&xt[((unsigned)sb << 6) + 2 * c2];
            const float wa = __expf(lrelu(as_[sa] + adn) - e_self);
            const float wb = __expf(lrelu(as_[sb] + adn) - e_self);
            den += wa + wb;
            acc0 += bf2f((unsigned short)(ua & 0xFFFF)) * wa + bf2f((unsigned short)(ub & 0xFFFF)) * wb;
            acc1 += bf2f((unsigned short)(ua >> 16)) * wa + bf2f((unsigned short)(ub >> 16)) * wb;
        }
        if (j < end) {
            const int s = csrS[j];
            const unsigned u = *(const unsigned*)&xt[((unsigned)s << 6) + 2 * c2];
            const float w = __expf(lrelu(as_[s] + adn) - e_self);
            den += w;
            acc0 += bf2f((unsigned short)(u & 0xFFFF)) * w;
            acc1 += bf2f((unsigned short)(u >> 16)) * w;
        }
        // combine parities
        acc0 += __shfl_xor(acc0, 32);
        acc1 += __shfl_xor(acc1, 32);
        den  += __shfl_xor(den, 32);
        // self loop (weight exactly 1)
        den += 1.f;
        const unsigned us = *(const unsigned*)&xt[((unsigned)node << 6) + 2 * c2];
        acc0 += bf2f((unsigned short)(us & 0xFFFF));
        acc1 += bf2f((unsigned short)(us >> 16));
        if (eo == 0) {
            const float inv = 1.f / den;
            unsigned short* mp = me + ((long)node << 6) + 2 * c2;
            const unsigned um = *(const unsigned*)mp;
            const float r0 = bf2f((unsigned short)(um & 0xFFFF)) + acc0 * inv + bg0;
            const float r1 = bf2f((unsigned short)(um >> 16)) + acc1 * inv + bg1;
            *(unsigned*)mp = (unsigned)bfr(r0) | ((unsigned)bfr(r1) << 16);
        }
    }
}

// Kernel E: MFMA GRU. x is bf16 (direct short8 loads); h stays f32.
__global__ __launch_bounds__(256) void kE(
    const unsigned short* __restrict__ x, const float* __restrict__ h,
    const float* __restrict__ w_ih, const float* __restrict__ w_hh,
    const float* __restrict__ b_ih, const float* __restrict__ b_hh,
    float* __restrict__ out)
{
    const int wv = threadIdx.x >> 6;
    const int lane = threadIdx.x & 63;
    const int lr = lane & 15;
    const int lk = lane >> 4;
    const int col = wv * 16 + lr;

    short8 Bf[6][2];
    #pragma unroll
    for (int g = 0; g < 6; ++g) {
        const float* W = (g < 3) ? w_ih : w_hh;
        const int row = (g % 3) * 64 + col;
        #pragma unroll
        for (int hf = 0; hf < 2; ++hf) {
            const float* p = W + (long)row * MEM + hf * 32 + lk * 8;
            short8 b;
            #pragma unroll
            for (int t = 0; t < 8; ++t) b[t] = (short)bfr(p[t]);
            Bf[g][hf] = b;
        }
    }
    const float bias[6] = { b_ih[col], b_ih[64 + col], b_ih[128 + col],
                            b_hh[col], b_hh[64 + col], b_hh[128 + col] };

    for (int mt = blockIdx.x; mt < N_NODES / 16; mt += gridDim.x) {
        const int n0 = mt * 16;
        const float* rh = h + (long)(n0 + lr) * MEM + lk * 8;
        short8 Ax[2], Ah[2];
        #pragma unroll
        for (int hf = 0; hf < 2; ++hf) {
            Ax[hf] = *(const short8*)(x + (long)(n0 + lr) * MEM + hf * 32 + lk * 8);
            short8 b;
            #pragma unroll
            for (int t = 0; t < 8; ++t) b[t] = (short)bfr(rh[hf * 32 + t]);
            Ah[hf] = b;
        }
        f32x4 acc[6];
        #pragma unroll
        for (int g = 0; g < 6; ++g) {
            f32x4 z; z[0] = bias[g]; z[1] = bias[g]; z[2] = bias[g]; z[3] = bias[g];
            acc[g] = z;
        }
        #pragma unroll
        for (int g = 0; g < 3; ++g) {
            acc[g] = __builtin_amdgcn_mfma_f32_16x16x32_bf16(Ax[0], Bf[g][0], acc[g], 0, 0, 0);
            acc[g] = __builtin_amdgcn_mfma_f32_16x16x32_bf16(Ax[1], Bf[g][1], acc[g], 0, 0, 0);
        }
        #pragma unroll
        for (int g = 3; g < 6; ++g) {
            acc[g] = __builtin_amdgcn_mfma_f32_16x16x32_bf16(Ah[0], Bf[g][0], acc[g], 0, 0, 0);
            acc[g] = __builtin_amdgcn_mfma_f32_16x16x32_bf16(Ah[1], Bf[g][1], acc[g], 0, 0, 0);
        }
        #pragma unroll
        for (int r = 0; r < 4; ++r) {
            const int node = n0 + lk * 4 + r;
            const long off = (long)node * MEM + col;
            const float hv = h[off];
            const float rr = 1.f / (1.f + __expf(-(acc[0][r] + acc[3][r])));
            const float zz = 1.f / (1.f + __expf(-(acc[1][r] + acc[4][r])));
            const float nn = tanhf(acc[2][r] + rr * acc[5][r]);
            out[off] = (1.f - zz) * nn + zz * hv;
        }
    }
}

extern "C" void kernel_launch(void* const* d_in, const int* in_sizes, int n_in,
                              void* d_out, int out_size, void* d_ws, size_t ws_size,
                              hipStream_t stream) {
    const float* state = (const float*)d_in[0];
    const float* goal  = (const float*)d_in[1];
    const float* mem   = (const float*)d_in[2];
    const int*   ei    = (const int*)d_in[3];
    const float* w_in  = (const float*)d_in[4];
    const float* b_in  = (const float*)d_in[5];
    const float* w_gat = (const float*)d_in[6];
    const float* att_s = (const float*)d_in[7];
    const float* att_d = (const float*)d_in[8];
    const float* b_gat = (const float*)d_in[9];
    const float* w_ih  = (const float*)d_in[10];
    const float* w_hh  = (const float*)d_in[11];
    const float* b_ih  = (const float*)d_in[12];
    const float* b_hh  = (const float*)d_in[13];
    float* out = (float*)d_out;

    const int* e_src = ei;
    const int* e_dst = ei + N_EDGES;

    // workspace layout
    unsigned short* me16 = (unsigned short*)d_ws;               // N*64 bf16 (becomes x)
    unsigned short* xt_bf = me16 + (long)N_NODES * MEM;         // N*64 bf16
    float* as_buf  = (float*)(xt_bf + (long)N_NODES * MEM);     // N
    float* ad_buf  = as_buf + N_NODES;                          // N
    int*   deg     = (int*)(ad_buf + N_NODES);                  // N
    int*   row_ptr = deg + N_NODES;                             // N+1
    int*   cursor  = row_ptr + N_NODES + 1;                     // N
    int*   bsums   = cursor + N_NODES;                          // NB
    int*   csrS    = bsums + NB;                                // E int (src only)

    hipMemsetAsync(deg, 0, N_NODES * sizeof(int), stream);

    hipLaunchKernelGGL(kA, dim3(1024), dim3(256), 0, stream,
        state, goal, mem, w_in, b_in, w_gat, att_s, att_d,
        me16, xt_bf, as_buf, ad_buf);

    hipLaunchKernelGGL(kH, dim3((N_EDGES / 4 + 255) / 256), dim3(256), 0, stream,
        (const int4*)e_dst, deg);
    hipLaunchKernelGGL(kS1, dim3(NB), dim3(256), 0, stream, deg, bsums);
    hipLaunchKernelGGL(kS2, dim3(1), dim3(512), 0, stream, bsums);
    hipLaunchKernelGGL(kS3, dim3(NB), dim3(256), 0, stream, deg, bsums, row_ptr, cursor);
    hipLaunchKernelGGL(kP, dim3((N_EDGES + 255) / 256), dim3(256), 0, stream,
        e_src, e_dst, cursor, csrS);

    hipLaunchKernelGGL(kG, dim3(2048), dim3(256), 0, stream,
        row_ptr, csrS, as_buf, ad_buf, xt_bf, b_gat, me16);

    hipLaunchKernelGGL(kE, dim3(1024), dim3(256), 0, stream,
        me16, mem, w_ih, w_hh, b_ih, b_hh, out);
}